// Round 11
// baseline (323.386 us; speedup 1.0000x reference)
//
#include <hip/hip_runtime.h>
#include <math.h>

#define DIN   32
#define F1    64   // H1*C1
#define F2    64   // H2*C2

// bf16 round-to-nearest-even pack of two floats into one uint
__device__ __forceinline__ unsigned bf16pack(float a, float b) {
    unsigned ua = __float_as_uint(a);
    unsigned ub = __float_as_uint(b);
    ua = (ua + 0x7FFFu + ((ua >> 16) & 1u)) >> 16;
    ub = (ub + 0x7FFFu + ((ub >> 16) & 1u)) >> 16;
    return ua | (ub << 16);
}

// ---------------- dense-linear body (shared) --------------------------------
// 32-node x 128-output tile, 256 threads, 2x8 micro-tile (16 acc regs).
// R4/R5 lesson: fatter micro-tiles spill to scratch; cap unroll.
template <int K>
__device__ __forceinline__ void lin_lr_body(int bid,
        const float* __restrict__ x,
        const float* __restrict__ Wl, const float* __restrict__ bl,
        const float* __restrict__ Wr, const float* __restrict__ br,
        float* __restrict__ xl, float* __restrict__ xr, int n) {
    __shared__ float Ash[32][K + 4];
    __shared__ float Wsh[K][128];
    const int t = threadIdx.x;
    const int node0 = bid * 32;

    for (int idx = t; idx < 32 * (K / 4); idx += 256) {
        int m = idx / (K / 4), kq = idx % (K / 4);
        float4 v = make_float4(0.f, 0.f, 0.f, 0.f);
        if (node0 + m < n) v = ((const float4*)(x + (size_t)(node0 + m) * K))[kq];
        *(float4*)&Ash[m][kq * 4] = v;
    }
    for (int idx = t; idx < K * 32; idx += 256) {
        int k = idx / 32, j4 = idx % 32;
        float4 v = (j4 < 16) ? ((const float4*)(Wl + (size_t)k * 64))[j4]
                             : ((const float4*)(Wr + (size_t)k * 64))[j4 - 16];
        *(float4*)&Wsh[k][j4 * 4] = v;
    }
    __syncthreads();

    const int ty = t >> 4;
    const int tx = t & 15;
    float acc0[8], acc1[8];
#pragma unroll
    for (int j = 0; j < 8; j++) { acc0[j] = 0.f; acc1[j] = 0.f; }

#pragma unroll 4
    for (int k = 0; k < K; k++) {
        float a0 = Ash[ty * 2 + 0][k];
        float a1 = Ash[ty * 2 + 1][k];
        float4 w0 = *(const float4*)&Wsh[k][tx * 8];
        float4 w1 = *(const float4*)&Wsh[k][tx * 8 + 4];
        acc0[0] += a0 * w0.x; acc0[1] += a0 * w0.y;
        acc0[2] += a0 * w0.z; acc0[3] += a0 * w0.w;
        acc0[4] += a0 * w1.x; acc0[5] += a0 * w1.y;
        acc0[6] += a0 * w1.z; acc0[7] += a0 * w1.w;
        acc1[0] += a1 * w0.x; acc1[1] += a1 * w0.y;
        acc1[2] += a1 * w0.z; acc1[3] += a1 * w0.w;
        acc1[4] += a1 * w1.x; acc1[5] += a1 * w1.y;
        acc1[6] += a1 * w1.z; acc1[7] += a1 * w1.w;
    }

    const float* bsrc = (tx < 8) ? bl : br;
    int jb = (tx < 8) ? tx * 8 : (tx - 8) * 8;
    float4 b0 = ((const float4*)(bsrc + jb))[0];
    float4 b1 = ((const float4*)(bsrc + jb))[1];
    float* dst = (tx < 8) ? xl : xr;
#pragma unroll
    for (int m = 0; m < 2; m++) {
        int node = node0 + ty * 2 + m;
        if (node >= n) continue;
        const float* ac = (m == 0) ? acc0 : acc1;
        float4 o0, o1;
        o0.x = ac[0] + b0.x; o0.y = ac[1] + b0.y;
        o0.z = ac[2] + b0.z; o0.w = ac[3] + b0.w;
        o1.x = ac[4] + b1.x; o1.y = ac[5] + b1.y;
        o1.z = ac[6] + b1.z; o1.w = ac[7] + b1.w;
        ((float4*)(dst + (size_t)node * 64 + jb))[0] = o0;
        ((float4*)(dst + (size_t)node * 64 + jb))[1] = o1;
    }
}

// ---------------- K1: bucket-count (LDS only) || lin1 ----------------------
__global__ __launch_bounds__(256, 2)
void fused_bcount_lin1(const int* __restrict__ dstr, int* __restrict__ cnt_mat,
                       int E, int Ec, int NB, int gridLin,
                       const float* __restrict__ x,
                       const float* __restrict__ Wl, const float* __restrict__ bl,
                       const float* __restrict__ Wr, const float* __restrict__ br,
                       float* __restrict__ xl, float* __restrict__ xr, int n) {
    __shared__ int hist[256];
    if ((int)blockIdx.x < gridLin) {
        lin_lr_body<DIN>(blockIdx.x, x, Wl, bl, Wr, br, xl, xr, n);
        return;
    }
    const int blk = blockIdx.x - gridLin;
    const int t = threadIdx.x;
    hist[t] = 0;
    __syncthreads();
    const int s0 = blk * Ec, s1 = min(E, s0 + Ec);
    for (int e = s0 + t; e < s1; e += 256)
        atomicAdd(&hist[dstr[e] >> 8], 1);
    __syncthreads();
    if (t < NB) cnt_mat[t * 256 + blk] = hist[t];
}

// ---------------- scan: block phase only (top-prefix recomputed inline) -----
__global__ void scan_blocks(const int* __restrict__ cnt, int* __restrict__ partial,
                            int* __restrict__ btot, int n) {
    __shared__ int sh[256];
    int t = threadIdx.x;
    int i = blockIdx.x * 256 + t;
    int v = (i < n) ? cnt[i] : 0;
    sh[t] = v; __syncthreads();
    for (int off = 1; off < 256; off <<= 1) {
        int x = (t >= off) ? sh[t - off] : 0;
        __syncthreads();
        sh[t] += x;
        __syncthreads();
    }
    if (i < n) partial[i] = sh[t] - v;
    if (t == 255) btot[blockIdx.x] = sh[t];
}

// ---------------- K3: scatter into bucket-partitioned intermediate ----------
// 8B record: lo = src | (dst&255)<<24 ; hi = bf16(ea0) | bf16(ea1)<<16.
// Per-chunk column bases computed inline: colsh[b] = partial[b*256+blk] +
// exclusive-prefix(btot)[b] — scan_add2 kernel + colbase array eliminated.
__global__ __launch_bounds__(256)
void scatter_buckets(const int* __restrict__ srcr, const int* __restrict__ dstr,
                     const float* __restrict__ ea,
                     const int* __restrict__ partial, const int* __restrict__ btot,
                     int2* __restrict__ inter, int E, int Ec, int NB) {
    __shared__ int sh[256];
    __shared__ int colsh[256];
    __shared__ int hist[256];
    const int blk = blockIdx.x;
    const int t = threadIdx.x;
    int bv = (t < NB) ? btot[t] : 0;
    sh[t] = bv;
    hist[t] = 0;
    __syncthreads();
    for (int off = 1; off < 256; off <<= 1) {
        int x = (t >= off) ? sh[t - off] : 0;
        __syncthreads();
        sh[t] += x;
        __syncthreads();
    }
    if (t < NB) colsh[t] = partial[t * 256 + blk] + (sh[t] - bv);
    __syncthreads();
    const int s0 = blk * Ec, s1 = min(E, s0 + Ec);
    for (int e = s0 + t; e < s1; e += 256) {
        int d = dstr[e];
        int b = d >> 8;
        int lr = atomicAdd(&hist[b], 1);
        float2 v = ((const float2*)ea)[e];
        int2 r;
        r.x = srcr[e] | ((d & 255) << 24);
        r.y = (int)bf16pack(v.x, v.y);
        inter[colsh[b] + lr] = r;
    }
}

// ---------------- K4: per-bucket CSR finalize -------------------------------
// Strips the dst byte on the final write (gat reads src directly). Block 0
// also writes 16 zero pad records at edges[E..E+15] so gat needs no clamps.
__global__ __launch_bounds__(256)
void bucket_csr(const int2* __restrict__ inter,
                const int* __restrict__ partial, const int* __restrict__ btot,
                int* __restrict__ row_ptr, int2* __restrict__ edges,
                int NB, int N, int E) {
    __shared__ int sh[256];
    __shared__ int cur[256];
    __shared__ int bnd[2];
    const int b = blockIdx.x, t = threadIdx.x;

    // recompute btot exclusive prefix; derive bstart/bend
    int bv = (t < NB) ? btot[t] : 0;
    sh[t] = bv;
    __syncthreads();
    for (int off = 1; off < 256; off <<= 1) {
        int x = (t >= off) ? sh[t - off] : 0;
        __syncthreads();
        sh[t] += x;
        __syncthreads();
    }
    if (t == b) bnd[0] = partial[b * 256] + (sh[t] - bv);
    if (t == b + 1 && t < NB) bnd[1] = partial[t * 256] + (sh[t] - bv);
    if (b + 1 >= NB && t == 0) bnd[1] = E;
    __syncthreads();
    const int bstart = bnd[0], bend = bnd[1];

    if (b == 0 && t < 16) { edges[E + t] = make_int2(0, 0); }

    sh[t] = 0;
    __syncthreads();
    for (int pos = bstart + t; pos < bend; pos += 256)
        atomicAdd(&sh[((unsigned)inter[pos].x) >> 24], 1);
    __syncthreads();
    int v = sh[t];
    __syncthreads();
    sh[t] = v; __syncthreads();
    for (int off = 1; off < 256; off <<= 1) {
        int x = (t >= off) ? sh[t - off] : 0;
        __syncthreads();
        sh[t] += x;
        __syncthreads();
    }
    int excl = sh[t] - v;
    cur[t] = excl;
    int node = b * 256 + t;
    if (node <= N) row_ptr[node] = bstart + excl;
    __syncthreads();
    for (int pos = bstart + t; pos < bend; pos += 256) {
        int2 r = inter[pos];
        int k = atomicAdd(&cur[((unsigned)r.x) >> 24], 1);
        r.x &= 0x00FFFFFF;                      // strip dst byte for gat
        edges[bstart + k] = r;
    }
}

__global__ __launch_bounds__(256, 2)
void lin_lr_tiled64(const float* __restrict__ x,
                    const float* __restrict__ Wl, const float* __restrict__ bl,
                    const float* __restrict__ Wr, const float* __restrict__ br,
                    float* __restrict__ xl, float* __restrict__ xr, int n) {
    lin_lr_body<F1>(blockIdx.x, x, Wl, bl, Wr, br, xl, xr, n);
}

// ---------------- GATv2 edge phase ------------------------------------------
// 8 edges/iteration (two independent 4-edge streams per 16-lane group; R10:
// doubling in-flight gathers recovered the VALU floor). 8B records, 16-record
// zero padding -> no address clamps. Max-free online softmax (logits bounded,
// glorot-scale inputs): one exp2/edge, merge butterfly is pure adds.
template <int H, int C, bool FUSE_HEADS>
__global__ __launch_bounds__(256)
void gat_kernel(const float* __restrict__ xl, const float* __restrict__ xr,
                const int* __restrict__ row_ptr, const int2* __restrict__ edges,
                const float* __restrict__ We, const float* __restrict__ att,
                const float* __restrict__ bias, float* __restrict__ hout,
                const float* __restrict__ wa, const float* __restrict__ ba,
                const float* __restrict__ wc, const float* __restrict__ bc,
                const float* __restrict__ ls, float* __restrict__ pout,
                int n) {
    constexpr int LPH = C / 4;
    if (FUSE_HEADS && blockIdx.x == 0 && threadIdx.x < 2)
        pout[(size_t)n * 2 + threadIdx.x] = expf(ls[threadIdx.x]);
    const int lane = threadIdx.x & 63;
    const int wid = (blockIdx.x * blockDim.x + threadIdx.x) >> 6;
    if (wid >= n) return;
    const int i = wid;
    const int g = lane >> 4;
    const int q = lane & 15;

    const float4* xl4 = (const float4*)xl;
    const float4 xri = ((const float4*)(xr + (size_t)i * 64))[q];
    const float4 we0 = ((const float4*)We)[q];
    const float4 we1 = ((const float4*)(We + 64))[q];
    float4 av = ((const float4*)att)[q];
    const float LOG2E = 1.4426950408889634f;
    av.x *= LOG2E; av.y *= LOG2E; av.z *= LOG2E; av.w *= LOG2E;

    float den = 0.f;
    float a0 = 0.f, a1 = 0.f, a2 = 0.f, a3 = 0.f;
    float s0 = 0.f, s1 = 0.f;

    const int e0 = row_ptr[i], e1 = row_ptr[i + 1];

    int2 rn0 = edges[e0 + g];
    int2 rn1 = edges[e0 + 4 + g];
    float4 xvn0 = xl4[(rn0.x << 4) + q];
    float4 xvn1 = xl4[(rn1.x << 4) + q];

    for (int eb = e0; eb < e1; eb += 8) {
        int2 r0 = rn0, r1 = rn1;
        float4 xv0 = xvn0, xv1 = xvn1;
        rn0 = edges[eb + 8 + g];
        rn1 = edges[eb + 12 + g];
        xvn0 = xl4[(rn0.x << 4) + q];
        xvn1 = xl4[(rn1.x << 4) + q];

        const bool v0 = (eb + g) < e1;
        const bool v1 = (eb + 4 + g) < e1;
        float ea00 = v0 ? __int_as_float(r0.y << 16) : 0.f;
        float ea01 = v0 ? __int_as_float(r0.y & 0xFFFF0000) : 0.f;
        float ea10 = v1 ? __int_as_float(r1.y << 16) : 0.f;
        float ea11 = v1 ? __int_as_float(r1.y & 0xFFFF0000) : 0.f;
        s0 += ea00 + ea10;
        s1 += ea01 + ea11;

        float y0 = xv0.x + fmaf(ea00, we0.x, fmaf(ea01, we1.x, xri.x));
        float y1 = xv0.y + fmaf(ea00, we0.y, fmaf(ea01, we1.y, xri.y));
        float y2 = xv0.z + fmaf(ea00, we0.z, fmaf(ea01, we1.z, xri.z));
        float y3 = xv0.w + fmaf(ea00, we0.w, fmaf(ea01, we1.w, xri.w));
        float u0 = xv1.x + fmaf(ea10, we0.x, fmaf(ea11, we1.x, xri.x));
        float u1 = xv1.y + fmaf(ea10, we0.y, fmaf(ea11, we1.y, xri.y));
        float u2 = xv1.z + fmaf(ea10, we0.z, fmaf(ea11, we1.z, xri.z));
        float u3 = xv1.w + fmaf(ea10, we0.w, fmaf(ea11, we1.w, xri.w));
        y0 = fmaxf(y0, 0.2f * y0); u0 = fmaxf(u0, 0.2f * u0);
        y1 = fmaxf(y1, 0.2f * y1); u1 = fmaxf(u1, 0.2f * u1);
        y2 = fmaxf(y2, 0.2f * y2); u2 = fmaxf(u2, 0.2f * u2);
        y3 = fmaxf(y3, 0.2f * y3); u3 = fmaxf(u3, 0.2f * u3);
        float l0 = fmaf(y0, av.x, fmaf(y1, av.y, fmaf(y2, av.z, y3 * av.w)));
        float l1 = fmaf(u0, av.x, fmaf(u1, av.y, fmaf(u2, av.z, u3 * av.w)));
#pragma unroll
        for (int m = 1; m < LPH; m <<= 1) {
            l0 += __shfl_xor(l0, m, 64);
            l1 += __shfl_xor(l1, m, 64);
        }
        float p0 = v0 ? exp2f(l0) : 0.f;
        float p1 = v1 ? exp2f(l1) : 0.f;
        den += p0 + p1;
        a0 = fmaf(p0, xv0.x, fmaf(p1, xv1.x, a0));
        a1 = fmaf(p0, xv0.y, fmaf(p1, xv1.y, a1));
        a2 = fmaf(p0, xv0.z, fmaf(p1, xv1.z, a2));
        a3 = fmaf(p0, xv0.w, fmaf(p1, xv1.w, a3));
    }

    // merge the 4 edge-slot groups — pure adds
#pragma unroll
    for (int m = 16; m < 64; m <<= 1) {
        den += __shfl_xor(den, m, 64);
        a0 += __shfl_xor(a0, m, 64);
        a1 += __shfl_xor(a1, m, 64);
        a2 += __shfl_xor(a2, m, 64);
        a3 += __shfl_xor(a3, m, 64);
        s0 += __shfl_xor(s0, m, 64);
        s1 += __shfl_xor(s1, m, 64);
    }

    // self-loop: attr = mean of incoming
    float degc = fmaxf((float)(e1 - e0), 1.0f);
    float la0 = s0 / degc, la1 = s1 / degc;
    const float4 xlv = xl4[(i << 4) + q];
    {
        float z0 = xlv.x + fmaf(la0, we0.x, fmaf(la1, we1.x, xri.x));
        float z1 = xlv.y + fmaf(la0, we0.y, fmaf(la1, we1.y, xri.y));
        float z2 = xlv.z + fmaf(la0, we0.z, fmaf(la1, we1.z, xri.z));
        float z3 = xlv.w + fmaf(la0, we0.w, fmaf(la1, we1.w, xri.w));
        z0 = fmaxf(z0, 0.2f * z0);
        z1 = fmaxf(z1, 0.2f * z1);
        z2 = fmaxf(z2, 0.2f * z2);
        z3 = fmaxf(z3, 0.2f * z3);
        float l = fmaf(z0, av.x, fmaf(z1, av.y, fmaf(z2, av.z, z3 * av.w)));
#pragma unroll
        for (int m = 1; m < LPH; m <<= 1) l += __shfl_xor(l, m, 64);
        float p = exp2f(l);
        den += p;
        a0 = fmaf(p, xlv.x, a0);
        a1 = fmaf(p, xlv.y, a1);
        a2 = fmaf(p, xlv.z, a2);
        a3 = fmaf(p, xlv.w, a3);
    }

    float rd = 1.0f / den;
    const float4 bv = ((const float4*)bias)[q];
    float4 o;
    o.x = fmaxf(fmaf(a0, rd, bv.x), 0.f);
    o.y = fmaxf(fmaf(a1, rd, bv.y), 0.f);
    o.z = fmaxf(fmaf(a2, rd, bv.z), 0.f);
    o.w = fmaxf(fmaf(a3, rd, bv.w), 0.f);

    if (!FUSE_HEADS) {
        if (g == 0) ((float4*)(hout + (size_t)i * 64))[q] = o;
    } else {
        float4 wa01 = ((const float4*)wa)[q * 2];
        float4 wa23 = ((const float4*)wa)[q * 2 + 1];
        float4 wcv  = ((const float4*)wc)[q];
        float d0 = o.x * wa01.x + o.y * wa01.z + o.z * wa23.x + o.w * wa23.z;
        float d1 = o.x * wa01.y + o.y * wa01.w + o.z * wa23.y + o.w * wa23.w;
        float d2 = o.x * wcv.x + o.y * wcv.y + o.z * wcv.z + o.w * wcv.w;
#pragma unroll
        for (int m = 1; m < 16; m <<= 1) {
            d0 += __shfl_xor(d0, m, 64);
            d1 += __shfl_xor(d1, m, 64);
            d2 += __shfl_xor(d2, m, 64);
        }
        if (lane == 0) {
            pout[(size_t)i * 2 + 0] = tanhf(d0 + ba[0]);
            pout[(size_t)i * 2 + 1] = tanhf(d1 + ba[1]);
            pout[(size_t)n * 2 + 2 + i] = d2 + bc[0];
        }
    }
}

// ---------------- launch ---------------------------------------------------

extern "C" void kernel_launch(void* const* d_in, const int* in_sizes, int n_in,
                              void* d_out, int out_size, void* d_ws, size_t ws_size,
                              hipStream_t stream) {
    const float* x    = (const float*)d_in[0];
    const int*   ei   = (const int*)  d_in[1];
    const float* ea   = (const float*)d_in[2];
    const float* w1l  = (const float*)d_in[3];
    const float* b1l  = (const float*)d_in[4];
    const float* w1r  = (const float*)d_in[5];
    const float* b1r  = (const float*)d_in[6];
    const float* w1e  = (const float*)d_in[7];
    const float* att1 = (const float*)d_in[8];
    const float* bias1= (const float*)d_in[9];
    const float* w2l  = (const float*)d_in[10];
    const float* b2l  = (const float*)d_in[11];
    const float* w2r  = (const float*)d_in[12];
    const float* b2r  = (const float*)d_in[13];
    const float* w2e  = (const float*)d_in[14];
    const float* att2 = (const float*)d_in[15];
    const float* bias2= (const float*)d_in[16];
    const float* wa   = (const float*)d_in[17];
    const float* ba   = (const float*)d_in[18];
    const float* wc   = (const float*)d_in[19];
    const float* bc   = (const float*)d_in[20];
    const float* ls   = (const float*)d_in[21];

    const int N = in_sizes[0] / DIN;
    const int E = in_sizes[2] / 2;
    const int* srcr = ei;
    const int* dstr = ei + E;

    const int NB = (N + 255) >> 8;           // node buckets (196)
    const int Ec = (E + 255) / 256;          // edges per chunk
    const int n2 = NB * 256;

    char* p = (char*)d_ws;
    auto alloc = [&](size_t bytes) -> void* {
        void* r = (void*)p;
        p += (bytes + 255) & ~(size_t)255;
        return r;
    };
    int*   cnt_mat = (int*)  alloc((size_t)n2 * 4);
    int*   partial = (int*)  alloc((size_t)n2 * 4);
    int*   btot    = (int*)  alloc(256 * 4);
    int*   row_ptr = (int*)  alloc((size_t)(N + 1) * 4);
    int2*  edges   = (int2*) alloc((size_t)(E + 16) * 8);
    float* xl      = (float*)alloc((size_t)N * F1 * 4);
    float* xr      = (float*)alloc((size_t)N * F1 * 4);
    float* h1      = (float*)alloc((size_t)N * F1 * 4);
    float* h2      = (float*)alloc((size_t)N * F2 * 4);
    // inter (E*8 = 13.2 MB) aliases h1 (+ spills into h2's adjacent region);
    // consumed by bucket_csr before h1/h2 are written.
    int2* inter = (int2*)h1;
    (void)ws_size; (void)n_in; (void)out_size;

    const int TB = 256;
    int nbScan = (n2 + TB - 1) / TB;         // 196
    int gridGemm = (N + 31) / 32;
    int gridWave = (N + 3) / 4;

    fused_bcount_lin1<<<gridGemm + 256, TB, 0, stream>>>(
        dstr, cnt_mat, E, Ec, NB, gridGemm, x, w1l, b1l, w1r, b1r, xl, xr, N);
    scan_blocks<<<nbScan, TB, 0, stream>>>(cnt_mat, partial, btot, n2);
    scatter_buckets<<<256, TB, 0, stream>>>(srcr, dstr, ea, partial, btot,
                                            inter, E, Ec, NB);
    bucket_csr<<<NB, TB, 0, stream>>>(inter, partial, btot, row_ptr, edges,
                                      NB, N, E);

    gat_kernel<4, 16, false><<<gridWave, TB, 0, stream>>>(
        xl, xr, row_ptr, edges, w1e, att1, bias1, h1,
        nullptr, nullptr, nullptr, nullptr, nullptr, nullptr, N);
    lin_lr_tiled64<<<gridGemm, TB, 0, stream>>>(h1, w2l, b2l, w2r, b2r, xl, xr, N);
    gat_kernel<2, 32, true><<<gridWave, TB, 0, stream>>>(
        xl, xr, row_ptr, edges, w2e, att2, bias2, h2,
        wa, ba, wc, bc, ls, (float*)d_out, N);
}

// Round 12
// 309.249 us; speedup vs baseline: 1.0457x; 1.0457x over previous
//
#include <hip/hip_runtime.h>
#include <math.h>

#define DIN   32
#define F1    64   // H1*C1
#define F2    64   // H2*C2

// bf16 round-to-nearest-even pack of two floats into one uint
__device__ __forceinline__ unsigned bf16pack(float a, float b) {
    unsigned ua = __float_as_uint(a);
    unsigned ub = __float_as_uint(b);
    ua = (ua + 0x7FFFu + ((ua >> 16) & 1u)) >> 16;
    ub = (ub + 0x7FFFu + ((ub >> 16) & 1u)) >> 16;
    return ua | (ub << 16);
}

// ---------------- dense-linear body (shared) --------------------------------
// 32-node x 128-output tile, 256 threads, 2x8 micro-tile (16 acc regs).
// R4/R5 lesson: fatter micro-tiles spill to scratch; cap unroll.
template <int K>
__device__ __forceinline__ void lin_lr_body(int bid,
        const float* __restrict__ x,
        const float* __restrict__ Wl, const float* __restrict__ bl,
        const float* __restrict__ Wr, const float* __restrict__ br,
        float* __restrict__ xl, float* __restrict__ xr, int n) {
    __shared__ float Ash[32][K + 4];
    __shared__ float Wsh[K][128];
    const int t = threadIdx.x;
    const int node0 = bid * 32;

    for (int idx = t; idx < 32 * (K / 4); idx += 256) {
        int m = idx / (K / 4), kq = idx % (K / 4);
        float4 v = make_float4(0.f, 0.f, 0.f, 0.f);
        if (node0 + m < n) v = ((const float4*)(x + (size_t)(node0 + m) * K))[kq];
        *(float4*)&Ash[m][kq * 4] = v;
    }
    for (int idx = t; idx < K * 32; idx += 256) {
        int k = idx / 32, j4 = idx % 32;
        float4 v = (j4 < 16) ? ((const float4*)(Wl + (size_t)k * 64))[j4]
                             : ((const float4*)(Wr + (size_t)k * 64))[j4 - 16];
        *(float4*)&Wsh[k][j4 * 4] = v;
    }
    __syncthreads();

    const int ty = t >> 4;
    const int tx = t & 15;
    float acc0[8], acc1[8];
#pragma unroll
    for (int j = 0; j < 8; j++) { acc0[j] = 0.f; acc1[j] = 0.f; }

#pragma unroll 4
    for (int k = 0; k < K; k++) {
        float a0 = Ash[ty * 2 + 0][k];
        float a1 = Ash[ty * 2 + 1][k];
        float4 w0 = *(const float4*)&Wsh[k][tx * 8];
        float4 w1 = *(const float4*)&Wsh[k][tx * 8 + 4];
        acc0[0] += a0 * w0.x; acc0[1] += a0 * w0.y;
        acc0[2] += a0 * w0.z; acc0[3] += a0 * w0.w;
        acc0[4] += a0 * w1.x; acc0[5] += a0 * w1.y;
        acc0[6] += a0 * w1.z; acc0[7] += a0 * w1.w;
        acc1[0] += a1 * w0.x; acc1[1] += a1 * w0.y;
        acc1[2] += a1 * w0.z; acc1[3] += a1 * w0.w;
        acc1[4] += a1 * w1.x; acc1[5] += a1 * w1.y;
        acc1[6] += a1 * w1.z; acc1[7] += a1 * w1.w;
    }

    const float* bsrc = (tx < 8) ? bl : br;
    int jb = (tx < 8) ? tx * 8 : (tx - 8) * 8;
    float4 b0 = ((const float4*)(bsrc + jb))[0];
    float4 b1 = ((const float4*)(bsrc + jb))[1];
    float* dst = (tx < 8) ? xl : xr;
#pragma unroll
    for (int m = 0; m < 2; m++) {
        int node = node0 + ty * 2 + m;
        if (node >= n) continue;
        const float* ac = (m == 0) ? acc0 : acc1;
        float4 o0, o1;
        o0.x = ac[0] + b0.x; o0.y = ac[1] + b0.y;
        o0.z = ac[2] + b0.z; o0.w = ac[3] + b0.w;
        o1.x = ac[4] + b1.x; o1.y = ac[5] + b1.y;
        o1.z = ac[6] + b1.z; o1.w = ac[7] + b1.w;
        ((float4*)(dst + (size_t)node * 64 + jb))[0] = o0;
        ((float4*)(dst + (size_t)node * 64 + jb))[1] = o1;
    }
}

// ---------------- K1: bucket-count + rank (LDS only) || lin1 ----------------
// rank[e] = within-(chunk,bucket) rank (coalesced write) — scatter_buckets
// then needs no second histogram (its loop becomes pure streaming).
__global__ __launch_bounds__(256, 2)
void fused_bcount_lin1(const int* __restrict__ dstr, int* __restrict__ cnt_mat,
                       int* __restrict__ rank, int E, int Ec, int NB, int gridLin,
                       const float* __restrict__ x,
                       const float* __restrict__ Wl, const float* __restrict__ bl,
                       const float* __restrict__ Wr, const float* __restrict__ br,
                       float* __restrict__ xl, float* __restrict__ xr, int n) {
    __shared__ int hist[256];
    if ((int)blockIdx.x < gridLin) {
        lin_lr_body<DIN>(blockIdx.x, x, Wl, bl, Wr, br, xl, xr, n);
        return;
    }
    const int blk = blockIdx.x - gridLin;
    const int t = threadIdx.x;
    hist[t] = 0;
    __syncthreads();
    const int s0 = blk * Ec, s1 = min(E, s0 + Ec);
    for (int e = s0 + t; e < s1; e += 256)
        rank[e] = atomicAdd(&hist[dstr[e] >> 8], 1);
    __syncthreads();
    if (t < NB) cnt_mat[t * 256 + blk] = hist[t];
}

// ---------------- scan: block phase only (top-prefix recomputed inline) -----
__global__ void scan_blocks(const int* __restrict__ cnt, int* __restrict__ partial,
                            int* __restrict__ btot, int n) {
    __shared__ int sh[256];
    int t = threadIdx.x;
    int i = blockIdx.x * 256 + t;
    int v = (i < n) ? cnt[i] : 0;
    sh[t] = v; __syncthreads();
    for (int off = 1; off < 256; off <<= 1) {
        int x = (t >= off) ? sh[t - off] : 0;
        __syncthreads();
        sh[t] += x;
        __syncthreads();
    }
    if (i < n) partial[i] = sh[t] - v;
    if (t == 255) btot[blockIdx.x] = sh[t];
}

// ---------------- K3: scatter into bucket-partitioned intermediate ----------
// TB=512 (8 waves/block, 1 block/CU): pure-streaming loop (rank precomputed).
// 8B record: lo = src | (dst&255)<<24 ; hi = bf16(ea0) | bf16(ea1)<<16.
__global__ __launch_bounds__(512)
void scatter_buckets(const int* __restrict__ srcr, const int* __restrict__ dstr,
                     const float* __restrict__ ea, const int* __restrict__ rank,
                     const int* __restrict__ partial, const int* __restrict__ btot,
                     int2* __restrict__ inter, int E, int Ec, int NB) {
    __shared__ int sh[256];
    __shared__ int colsh[256];
    const int blk = blockIdx.x;
    const int t = threadIdx.x;
    int bv = 0;
    if (t < 256) { bv = (t < NB) ? btot[t] : 0; sh[t] = bv; }
    __syncthreads();
    for (int off = 1; off < 256; off <<= 1) {
        int x = (t >= off && t < 256) ? sh[t - off] : 0;
        __syncthreads();
        if (t < 256) sh[t] += x;
        __syncthreads();
    }
    if (t < NB) colsh[t] = partial[t * 256 + blk] + (sh[t] - bv);
    __syncthreads();
    const int s0 = blk * Ec, s1 = min(E, s0 + Ec);
    for (int e = s0 + t; e < s1; e += 512) {
        int d = dstr[e];
        float2 v = ((const float2*)ea)[e];
        int2 r;
        r.x = srcr[e] | ((d & 255) << 24);
        r.y = (int)bf16pack(v.x, v.y);
        inter[colsh[d >> 8] + rank[e]] = r;
    }
}

// ---------------- K4: per-bucket CSR finalize (TB=512) ----------------------
// Strips the dst byte on the final write. Block 0 writes 16 zero pad records
// at edges[E..E+15] so gat needs no address clamps.
__global__ __launch_bounds__(512)
void bucket_csr(const int2* __restrict__ inter,
                const int* __restrict__ partial, const int* __restrict__ btot,
                int* __restrict__ row_ptr, int2* __restrict__ edges,
                int NB, int N, int E) {
    __shared__ int sh[256];
    __shared__ int cur[256];
    __shared__ int bnd[2];
    const int b = blockIdx.x, t = threadIdx.x;

    // recompute btot exclusive prefix; derive bstart/bend
    int bv = 0;
    if (t < 256) { bv = (t < NB) ? btot[t] : 0; sh[t] = bv; }
    __syncthreads();
    for (int off = 1; off < 256; off <<= 1) {
        int x = (t >= off && t < 256) ? sh[t - off] : 0;
        __syncthreads();
        if (t < 256) sh[t] += x;
        __syncthreads();
    }
    if (t == b) bnd[0] = partial[b * 256] + (sh[t] - bv);
    if (t == b + 1 && t < NB) bnd[1] = partial[t * 256] + (sh[t] - bv);
    if (b + 1 >= NB && t == 0) bnd[1] = E;
    __syncthreads();
    const int bstart = bnd[0], bend = bnd[1];

    if (b == 0 && t < 16) { edges[E + t] = make_int2(0, 0); }

    if (t < 256) sh[t] = 0;
    __syncthreads();
    for (int pos = bstart + t; pos < bend; pos += 512)
        atomicAdd(&sh[((unsigned)inter[pos].x) >> 24], 1);
    __syncthreads();
    int v = 0;
    if (t < 256) v = sh[t];
    __syncthreads();
    if (t < 256) sh[t] = v;
    __syncthreads();
    for (int off = 1; off < 256; off <<= 1) {
        int x = (t >= off && t < 256) ? sh[t - off] : 0;
        __syncthreads();
        if (t < 256) sh[t] += x;
        __syncthreads();
    }
    if (t < 256) {
        int excl = sh[t] - v;
        cur[t] = excl;
        int node = b * 256 + t;
        if (node <= N) row_ptr[node] = bstart + excl;
    }
    __syncthreads();
    for (int pos = bstart + t; pos < bend; pos += 512) {
        int2 r = inter[pos];
        int k = atomicAdd(&cur[((unsigned)r.x) >> 24], 1);
        r.x &= 0x00FFFFFF;                      // strip dst byte for gat
        edges[bstart + k] = r;
    }
}

__global__ __launch_bounds__(256, 2)
void lin_lr_tiled64(const float* __restrict__ x,
                    const float* __restrict__ Wl, const float* __restrict__ bl,
                    const float* __restrict__ Wr, const float* __restrict__ br,
                    float* __restrict__ xl, float* __restrict__ xr, int n) {
    lin_lr_body<F1>(blockIdx.x, x, Wl, bl, Wr, br, xl, xr, n);
}

// ---------------- GATv2 edge phase ------------------------------------------
// 8 edges/iteration, two independent 4-edge streams (R10: in-flight gathers
// recover the VALU floor). Remainder-split: main loop is mask-free; one
// masked tail iteration handles the <=7 leftover edges. 16 zero pad records
// make all prefetch addresses safe. Max-free online softmax (logits bounded).
template <int H, int C, bool FUSE_HEADS>
__global__ __launch_bounds__(256)
void gat_kernel(const float* __restrict__ xl, const float* __restrict__ xr,
                const int* __restrict__ row_ptr, const int2* __restrict__ edges,
                const float* __restrict__ We, const float* __restrict__ att,
                const float* __restrict__ bias, float* __restrict__ hout,
                const float* __restrict__ wa, const float* __restrict__ ba,
                const float* __restrict__ wc, const float* __restrict__ bc,
                const float* __restrict__ ls, float* __restrict__ pout,
                int n) {
    constexpr int LPH = C / 4;
    if (FUSE_HEADS && blockIdx.x == 0 && threadIdx.x < 2)
        pout[(size_t)n * 2 + threadIdx.x] = expf(ls[threadIdx.x]);
    const int lane = threadIdx.x & 63;
    const int wid = (blockIdx.x * blockDim.x + threadIdx.x) >> 6;
    if (wid >= n) return;
    const int i = wid;
    const int g = lane >> 4;
    const int q = lane & 15;

    const float4* xl4 = (const float4*)xl;
    const float4 xri = ((const float4*)(xr + (size_t)i * 64))[q];
    const float4 we0 = ((const float4*)We)[q];
    const float4 we1 = ((const float4*)(We + 64))[q];
    float4 av = ((const float4*)att)[q];
    const float LOG2E = 1.4426950408889634f;
    av.x *= LOG2E; av.y *= LOG2E; av.z *= LOG2E; av.w *= LOG2E;

    float den = 0.f;
    float a0 = 0.f, a1 = 0.f, a2 = 0.f, a3 = 0.f;
    float s0 = 0.f, s1 = 0.f;

    const int e0 = row_ptr[i], e1 = row_ptr[i + 1];
    const int emain = e0 + ((e1 - e0) & ~7);

    int2 rn0 = edges[e0 + g];
    int2 rn1 = edges[e0 + 4 + g];
    float4 xvn0 = xl4[(rn0.x << 4) + q];
    float4 xvn1 = xl4[(rn1.x << 4) + q];

    for (int eb = e0; eb < emain; eb += 8) {
        int2 r0 = rn0, r1 = rn1;
        float4 xv0 = xvn0, xv1 = xvn1;
        rn0 = edges[eb + 8 + g];
        rn1 = edges[eb + 12 + g];
        xvn0 = xl4[(rn0.x << 4) + q];
        xvn1 = xl4[(rn1.x << 4) + q];

        float ea00 = __int_as_float(r0.y << 16);
        float ea01 = __int_as_float(r0.y & 0xFFFF0000);
        float ea10 = __int_as_float(r1.y << 16);
        float ea11 = __int_as_float(r1.y & 0xFFFF0000);
        s0 += ea00 + ea10;
        s1 += ea01 + ea11;

        float y0 = xv0.x + fmaf(ea00, we0.x, fmaf(ea01, we1.x, xri.x));
        float y1 = xv0.y + fmaf(ea00, we0.y, fmaf(ea01, we1.y, xri.y));
        float y2 = xv0.z + fmaf(ea00, we0.z, fmaf(ea01, we1.z, xri.z));
        float y3 = xv0.w + fmaf(ea00, we0.w, fmaf(ea01, we1.w, xri.w));
        float u0 = xv1.x + fmaf(ea10, we0.x, fmaf(ea11, we1.x, xri.x));
        float u1 = xv1.y + fmaf(ea10, we0.y, fmaf(ea11, we1.y, xri.y));
        float u2 = xv1.z + fmaf(ea10, we0.z, fmaf(ea11, we1.z, xri.z));
        float u3 = xv1.w + fmaf(ea10, we0.w, fmaf(ea11, we1.w, xri.w));
        y0 = fmaxf(y0, 0.2f * y0); u0 = fmaxf(u0, 0.2f * u0);
        y1 = fmaxf(y1, 0.2f * y1); u1 = fmaxf(u1, 0.2f * u1);
        y2 = fmaxf(y2, 0.2f * y2); u2 = fmaxf(u2, 0.2f * u2);
        y3 = fmaxf(y3, 0.2f * y3); u3 = fmaxf(u3, 0.2f * u3);
        float l0 = fmaf(y0, av.x, fmaf(y1, av.y, fmaf(y2, av.z, y3 * av.w)));
        float l1 = fmaf(u0, av.x, fmaf(u1, av.y, fmaf(u2, av.z, u3 * av.w)));
#pragma unroll
        for (int m = 1; m < LPH; m <<= 1) {
            l0 += __shfl_xor(l0, m, 64);
            l1 += __shfl_xor(l1, m, 64);
        }
        float p0 = exp2f(l0);
        float p1 = exp2f(l1);
        den += p0 + p1;
        a0 = fmaf(p0, xv0.x, fmaf(p1, xv1.x, a0));
        a1 = fmaf(p0, xv0.y, fmaf(p1, xv1.y, a1));
        a2 = fmaf(p0, xv0.z, fmaf(p1, xv1.z, a2));
        a3 = fmaf(p0, xv0.w, fmaf(p1, xv1.w, a3));
    }

    // masked tail (<=7 edges), uses the already-prefetched registers
    if (emain < e1) {
        const bool v0 = (emain + g) < e1;
        const bool v1 = (emain + 4 + g) < e1;
        float ea00 = v0 ? __int_as_float(rn0.y << 16) : 0.f;
        float ea01 = v0 ? __int_as_float(rn0.y & 0xFFFF0000) : 0.f;
        float ea10 = v1 ? __int_as_float(rn1.y << 16) : 0.f;
        float ea11 = v1 ? __int_as_float(rn1.y & 0xFFFF0000) : 0.f;
        s0 += ea00 + ea10;
        s1 += ea01 + ea11;
        float y0 = xvn0.x + fmaf(ea00, we0.x, fmaf(ea01, we1.x, xri.x));
        float y1 = xvn0.y + fmaf(ea00, we0.y, fmaf(ea01, we1.y, xri.y));
        float y2 = xvn0.z + fmaf(ea00, we0.z, fmaf(ea01, we1.z, xri.z));
        float y3 = xvn0.w + fmaf(ea00, we0.w, fmaf(ea01, we1.w, xri.w));
        float u0 = xvn1.x + fmaf(ea10, we0.x, fmaf(ea11, we1.x, xri.x));
        float u1 = xvn1.y + fmaf(ea10, we0.y, fmaf(ea11, we1.y, xri.y));
        float u2 = xvn1.z + fmaf(ea10, we0.z, fmaf(ea11, we1.z, xri.z));
        float u3 = xvn1.w + fmaf(ea10, we0.w, fmaf(ea11, we1.w, xri.w));
        y0 = fmaxf(y0, 0.2f * y0); u0 = fmaxf(u0, 0.2f * u0);
        y1 = fmaxf(y1, 0.2f * y1); u1 = fmaxf(u1, 0.2f * u1);
        y2 = fmaxf(y2, 0.2f * y2); u2 = fmaxf(u2, 0.2f * u2);
        y3 = fmaxf(y3, 0.2f * y3); u3 = fmaxf(u3, 0.2f * u3);
        float l0 = fmaf(y0, av.x, fmaf(y1, av.y, fmaf(y2, av.z, y3 * av.w)));
        float l1 = fmaf(u0, av.x, fmaf(u1, av.y, fmaf(u2, av.z, u3 * av.w)));
#pragma unroll
        for (int m = 1; m < LPH; m <<= 1) {
            l0 += __shfl_xor(l0, m, 64);
            l1 += __shfl_xor(l1, m, 64);
        }
        float p0 = v0 ? exp2f(l0) : 0.f;
        float p1 = v1 ? exp2f(l1) : 0.f;
        den += p0 + p1;
        a0 = fmaf(p0, xvn0.x, fmaf(p1, xvn1.x, a0));
        a1 = fmaf(p0, xvn0.y, fmaf(p1, xvn1.y, a1));
        a2 = fmaf(p0, xvn0.z, fmaf(p1, xvn1.z, a2));
        a3 = fmaf(p0, xvn0.w, fmaf(p1, xvn1.w, a3));
    }

    // merge the 4 edge-slot groups — pure adds
#pragma unroll
    for (int m = 16; m < 64; m <<= 1) {
        den += __shfl_xor(den, m, 64);
        a0 += __shfl_xor(a0, m, 64);
        a1 += __shfl_xor(a1, m, 64);
        a2 += __shfl_xor(a2, m, 64);
        a3 += __shfl_xor(a3, m, 64);
        s0 += __shfl_xor(s0, m, 64);
        s1 += __shfl_xor(s1, m, 64);
    }

    // self-loop: attr = mean of incoming
    float degc = fmaxf((float)(e1 - e0), 1.0f);
    float la0 = s0 / degc, la1 = s1 / degc;
    const float4 xlv = xl4[(i << 4) + q];
    {
        float z0 = xlv.x + fmaf(la0, we0.x, fmaf(la1, we1.x, xri.x));
        float z1 = xlv.y + fmaf(la0, we0.y, fmaf(la1, we1.y, xri.y));
        float z2 = xlv.z + fmaf(la0, we0.z, fmaf(la1, we1.z, xri.z));
        float z3 = xlv.w + fmaf(la0, we0.w, fmaf(la1, we1.w, xri.w));
        z0 = fmaxf(z0, 0.2f * z0);
        z1 = fmaxf(z1, 0.2f * z1);
        z2 = fmaxf(z2, 0.2f * z2);
        z3 = fmaxf(z3, 0.2f * z3);
        float l = fmaf(z0, av.x, fmaf(z1, av.y, fmaf(z2, av.z, z3 * av.w)));
#pragma unroll
        for (int m = 1; m < LPH; m <<= 1) l += __shfl_xor(l, m, 64);
        float p = exp2f(l);
        den += p;
        a0 = fmaf(p, xlv.x, a0);
        a1 = fmaf(p, xlv.y, a1);
        a2 = fmaf(p, xlv.z, a2);
        a3 = fmaf(p, xlv.w, a3);
    }

    float rd = 1.0f / den;
    const float4 bv = ((const float4*)bias)[q];
    float4 o;
    o.x = fmaxf(fmaf(a0, rd, bv.x), 0.f);
    o.y = fmaxf(fmaf(a1, rd, bv.y), 0.f);
    o.z = fmaxf(fmaf(a2, rd, bv.z), 0.f);
    o.w = fmaxf(fmaf(a3, rd, bv.w), 0.f);

    if (!FUSE_HEADS) {
        if (g == 0) ((float4*)(hout + (size_t)i * 64))[q] = o;
    } else {
        float4 wa01 = ((const float4*)wa)[q * 2];
        float4 wa23 = ((const float4*)wa)[q * 2 + 1];
        float4 wcv  = ((const float4*)wc)[q];
        float d0 = o.x * wa01.x + o.y * wa01.z + o.z * wa23.x + o.w * wa23.z;
        float d1 = o.x * wa01.y + o.y * wa01.w + o.z * wa23.y + o.w * wa23.w;
        float d2 = o.x * wcv.x + o.y * wcv.y + o.z * wcv.z + o.w * wcv.w;
#pragma unroll
        for (int m = 1; m < 16; m <<= 1) {
            d0 += __shfl_xor(d0, m, 64);
            d1 += __shfl_xor(d1, m, 64);
            d2 += __shfl_xor(d2, m, 64);
        }
        if (lane == 0) {
            pout[(size_t)i * 2 + 0] = tanhf(d0 + ba[0]);
            pout[(size_t)i * 2 + 1] = tanhf(d1 + ba[1]);
            pout[(size_t)n * 2 + 2 + i] = d2 + bc[0];
        }
    }
}

// ---------------- launch ---------------------------------------------------

extern "C" void kernel_launch(void* const* d_in, const int* in_sizes, int n_in,
                              void* d_out, int out_size, void* d_ws, size_t ws_size,
                              hipStream_t stream) {
    const float* x    = (const float*)d_in[0];
    const int*   ei   = (const int*)  d_in[1];
    const float* ea   = (const float*)d_in[2];
    const float* w1l  = (const float*)d_in[3];
    const float* b1l  = (const float*)d_in[4];
    const float* w1r  = (const float*)d_in[5];
    const float* b1r  = (const float*)d_in[6];
    const float* w1e  = (const float*)d_in[7];
    const float* att1 = (const float*)d_in[8];
    const float* bias1= (const float*)d_in[9];
    const float* w2l  = (const float*)d_in[10];
    const float* b2l  = (const float*)d_in[11];
    const float* w2r  = (const float*)d_in[12];
    const float* b2r  = (const float*)d_in[13];
    const float* w2e  = (const float*)d_in[14];
    const float* att2 = (const float*)d_in[15];
    const float* bias2= (const float*)d_in[16];
    const float* wa   = (const float*)d_in[17];
    const float* ba   = (const float*)d_in[18];
    const float* wc   = (const float*)d_in[19];
    const float* bc   = (const float*)d_in[20];
    const float* ls   = (const float*)d_in[21];

    const int N = in_sizes[0] / DIN;
    const int E = in_sizes[2] / 2;
    const int* srcr = ei;
    const int* dstr = ei + E;

    const int NB = (N + 255) >> 8;           // node buckets (196)
    const int Ec = (E + 255) / 256;          // edges per chunk
    const int n2 = NB * 256;

    char* p = (char*)d_ws;
    auto alloc = [&](size_t bytes) -> void* {
        void* r = (void*)p;
        p += (bytes + 255) & ~(size_t)255;
        return r;
    };
    int*   cnt_mat = (int*)  alloc((size_t)n2 * 4);
    int*   partial = (int*)  alloc((size_t)n2 * 4);
    int*   btot    = (int*)  alloc(256 * 4);
    int*   rank    = (int*)  alloc((size_t)E * 4);
    int*   row_ptr = (int*)  alloc((size_t)(N + 1) * 4);
    int2*  edges   = (int2*) alloc((size_t)(E + 16) * 8);
    float* xl      = (float*)alloc((size_t)N * F1 * 4);
    float* xr      = (float*)alloc((size_t)N * F1 * 4);
    float* h1      = (float*)alloc((size_t)N * F1 * 4);
    float* h2      = (float*)alloc((size_t)N * F2 * 4);
    // inter (E*8 = 13.2 MB) aliases h1 (+ start of h2); consumed by
    // bucket_csr before h1/h2 are written.
    int2* inter = (int2*)h1;
    (void)ws_size; (void)n_in; (void)out_size;

    const int TB = 256;
    int nbScan = (n2 + TB - 1) / TB;         // 196
    int gridGemm = (N + 31) / 32;
    int gridWave = (N + 3) / 4;

    fused_bcount_lin1<<<gridGemm + 256, TB, 0, stream>>>(
        dstr, cnt_mat, rank, E, Ec, NB, gridGemm, x, w1l, b1l, w1r, b1r, xl, xr, N);
    scan_blocks<<<nbScan, TB, 0, stream>>>(cnt_mat, partial, btot, n2);
    scatter_buckets<<<256, 512, 0, stream>>>(srcr, dstr, ea, rank, partial, btot,
                                             inter, E, Ec, NB);
    bucket_csr<<<NB, 512, 0, stream>>>(inter, partial, btot, row_ptr, edges,
                                       NB, N, E);

    gat_kernel<4, 16, false><<<gridWave, TB, 0, stream>>>(
        xl, xr, row_ptr, edges, w1e, att1, bias1, h1,
        nullptr, nullptr, nullptr, nullptr, nullptr, nullptr, N);
    lin_lr_tiled64<<<gridGemm, TB, 0, stream>>>(h1, w2l, b2l, w2r, b2r, xl, xr, N);
    gat_kernel<2, 32, true><<<gridWave, TB, 0, stream>>>(
        xl, xr, row_ptr, edges, w2e, att2, bias2, h2,
        wa, ba, wc, bc, ls, (float*)d_out, N);
}

// Round 13
// 303.939 us; speedup vs baseline: 1.0640x; 1.0175x over previous
//
#include <hip/hip_runtime.h>
#include <math.h>

#define DIN   32
#define F1    64   // H1*C1
#define F2    64   // H2*C2

// bf16 round-to-nearest-even pack of two floats into one uint
__device__ __forceinline__ unsigned bf16pack(float a, float b) {
    unsigned ua = __float_as_uint(a);
    unsigned ub = __float_as_uint(b);
    ua = (ua + 0x7FFFu + ((ua >> 16) & 1u)) >> 16;
    ub = (ub + 0x7FFFu + ((ub >> 16) & 1u)) >> 16;
    return ua | (ub << 16);
}

// ---------------- dense-linear body (shared) --------------------------------
// 32-node x 128-output tile, 256 threads, 2x8 micro-tile (16 acc regs).
// R4/R5 lesson: fatter micro-tiles spill to scratch; cap unroll.
template <int K>
__device__ __forceinline__ void lin_lr_body(int bid,
        const float* __restrict__ x,
        const float* __restrict__ Wl, const float* __restrict__ bl,
        const float* __restrict__ Wr, const float* __restrict__ br,
        float* __restrict__ xl, float* __restrict__ xr, int n) {
    __shared__ float Ash[32][K + 4];
    __shared__ float Wsh[K][128];
    const int t = threadIdx.x;
    const int node0 = bid * 32;

    for (int idx = t; idx < 32 * (K / 4); idx += 256) {
        int m = idx / (K / 4), kq = idx % (K / 4);
        float4 v = make_float4(0.f, 0.f, 0.f, 0.f);
        if (node0 + m < n) v = ((const float4*)(x + (size_t)(node0 + m) * K))[kq];
        *(float4*)&Ash[m][kq * 4] = v;
    }
    for (int idx = t; idx < K * 32; idx += 256) {
        int k = idx / 32, j4 = idx % 32;
        float4 v = (j4 < 16) ? ((const float4*)(Wl + (size_t)k * 64))[j4]
                             : ((const float4*)(Wr + (size_t)k * 64))[j4 - 16];
        *(float4*)&Wsh[k][j4 * 4] = v;
    }
    __syncthreads();

    const int ty = t >> 4;
    const int tx = t & 15;
    float acc0[8], acc1[8];
#pragma unroll
    for (int j = 0; j < 8; j++) { acc0[j] = 0.f; acc1[j] = 0.f; }

#pragma unroll 4
    for (int k = 0; k < K; k++) {
        float a0 = Ash[ty * 2 + 0][k];
        float a1 = Ash[ty * 2 + 1][k];
        float4 w0 = *(const float4*)&Wsh[k][tx * 8];
        float4 w1 = *(const float4*)&Wsh[k][tx * 8 + 4];
        acc0[0] += a0 * w0.x; acc0[1] += a0 * w0.y;
        acc0[2] += a0 * w0.z; acc0[3] += a0 * w0.w;
        acc0[4] += a0 * w1.x; acc0[5] += a0 * w1.y;
        acc0[6] += a0 * w1.z; acc0[7] += a0 * w1.w;
        acc1[0] += a1 * w0.x; acc1[1] += a1 * w0.y;
        acc1[2] += a1 * w0.z; acc1[3] += a1 * w0.w;
        acc1[4] += a1 * w1.x; acc1[5] += a1 * w1.y;
        acc1[6] += a1 * w1.z; acc1[7] += a1 * w1.w;
    }

    const float* bsrc = (tx < 8) ? bl : br;
    int jb = (tx < 8) ? tx * 8 : (tx - 8) * 8;
    float4 b0 = ((const float4*)(bsrc + jb))[0];
    float4 b1 = ((const float4*)(bsrc + jb))[1];
    float* dst = (tx < 8) ? xl : xr;
#pragma unroll
    for (int m = 0; m < 2; m++) {
        int node = node0 + ty * 2 + m;
        if (node >= n) continue;
        const float* ac = (m == 0) ? acc0 : acc1;
        float4 o0, o1;
        o0.x = ac[0] + b0.x; o0.y = ac[1] + b0.y;
        o0.z = ac[2] + b0.z; o0.w = ac[3] + b0.w;
        o1.x = ac[4] + b1.x; o1.y = ac[5] + b1.y;
        o1.z = ac[6] + b1.z; o1.w = ac[7] + b1.w;
        ((float4*)(dst + (size_t)node * 64 + jb))[0] = o0;
        ((float4*)(dst + (size_t)node * 64 + jb))[1] = o1;
    }
}

// ---------------- K1: bucket-count + rank + cursor reserve || lin1 ----------
// No scan pass: each chunk reserves its per-bucket space with ONE global
// atomicAdd(&cursor[b], hist[b]) (50k total atomics across the grid).
// chunkoff[blk*256+b] = within-bucket base for this chunk's edges.
__global__ __launch_bounds__(256, 2)
void fused_bcount_lin1(const int* __restrict__ dstr, int* __restrict__ cursor,
                       int* __restrict__ chunkoff, int* __restrict__ rank,
                       int E, int Ec, int NB, int gridLin,
                       const float* __restrict__ x,
                       const float* __restrict__ Wl, const float* __restrict__ bl,
                       const float* __restrict__ Wr, const float* __restrict__ br,
                       float* __restrict__ xl, float* __restrict__ xr, int n) {
    __shared__ int hist[256];
    if ((int)blockIdx.x < gridLin) {
        lin_lr_body<DIN>(blockIdx.x, x, Wl, bl, Wr, br, xl, xr, n);
        return;
    }
    const int blk = blockIdx.x - gridLin;
    const int t = threadIdx.x;
    hist[t] = 0;
    __syncthreads();
    const int s0 = blk * Ec, s1 = min(E, s0 + Ec);
    for (int e = s0 + t; e < s1; e += 256)
        rank[e] = atomicAdd(&hist[dstr[e] >> 8], 1);
    __syncthreads();
    if (t < NB) {
        int h = hist[t];
        chunkoff[blk * 256 + t] = h ? atomicAdd(&cursor[t], h) : 0;
    }
}

// ---------------- K3: scatter into fixed-cap bucket regions -----------------
// TB=512, pure streaming (rank precomputed). 8B record:
// lo = src | (dst&255)<<24 ; hi = bf16(ea0) | bf16(ea1)<<16.
__global__ __launch_bounds__(512)
void scatter_buckets(const int* __restrict__ srcr, const int* __restrict__ dstr,
                     const float* __restrict__ ea, const int* __restrict__ rank,
                     const int* __restrict__ chunkoff,
                     int2* __restrict__ inter, int E, int Ec, int NB, int cap) {
    __shared__ int colsh[256];
    const int blk = blockIdx.x;
    const int t = threadIdx.x;
    if (t < 256) colsh[t] = (t < NB) ? (t * cap + chunkoff[blk * 256 + t]) : 0;
    __syncthreads();
    const int s0 = blk * Ec, s1 = min(E, s0 + Ec);
    for (int e = s0 + t; e < s1; e += 512) {
        int d = dstr[e];
        float2 v = ((const float2*)ea)[e];
        int2 r;
        r.x = srcr[e] | ((d & 255) << 24);
        r.y = (int)bf16pack(v.x, v.y);
        inter[colsh[d >> 8] + rank[e]] = r;
    }
}

// ---------------- K4: per-bucket CSR finalize (TB=512) ----------------------
// bstart = b*cap (fixed), bend = bstart + cursor[b]. Writes rs/re per node
// (row_ptr can't span the inter-bucket gaps) and zeroes the gap region so
// gat's unguarded prefetches read harmless zero records.
__global__ __launch_bounds__(512)
void bucket_csr(const int2* __restrict__ inter, const int* __restrict__ cursor,
                int* __restrict__ rs, int* __restrict__ re,
                int2* __restrict__ edges, int NB, int N, int cap) {
    __shared__ int sh[256];
    __shared__ int cur[256];
    const int b = blockIdx.x, t = threadIdx.x;
    const int bstart = b * cap;
    const int bend = bstart + cursor[b];

    if (t < 256) sh[t] = 0;
    __syncthreads();
    for (int pos = bstart + t; pos < bend; pos += 512)
        atomicAdd(&sh[((unsigned)inter[pos].x) >> 24], 1);
    __syncthreads();
    int v = 0;
    if (t < 256) v = sh[t];
    __syncthreads();
    if (t < 256) sh[t] = v;
    __syncthreads();
    for (int off = 1; off < 256; off <<= 1) {
        int x = (t >= off && t < 256) ? sh[t - off] : 0;
        __syncthreads();
        if (t < 256) sh[t] += x;
        __syncthreads();
    }
    if (t < 256) {
        int excl = sh[t] - v;
        cur[t] = excl;
        int node = b * 256 + t;
        if (node < N) { rs[node] = bstart + excl; re[node] = bstart + excl + v; }
    }
    __syncthreads();
    for (int pos = bstart + t; pos < bend; pos += 512) {
        int2 r = inter[pos];
        int k = atomicAdd(&cur[((unsigned)r.x) >> 24], 1);
        r.x &= 0x00FFFFFF;                      // strip dst byte for gat
        edges[bstart + k] = r;
    }
    // zero the gap so gat prefetches past re[] read {src=0, ea=0} records
    int zend = (b + 1) * cap + ((b == NB - 1) ? 64 : 0);
    for (int pos = bend + t; pos < zend; pos += 512)
        edges[pos] = make_int2(0, 0);
}

__global__ __launch_bounds__(256, 2)
void lin_lr_tiled64(const float* __restrict__ x,
                    const float* __restrict__ Wl, const float* __restrict__ bl,
                    const float* __restrict__ Wr, const float* __restrict__ br,
                    float* __restrict__ xl, float* __restrict__ xr, int n) {
    lin_lr_body<F1>(blockIdx.x, x, Wl, bl, Wr, br, xl, xr, n);
}

// ---------------- GATv2 edge phase ------------------------------------------
// R11 form (measured best: VGPR 32, occ 70%): 8 edges/iter, two independent
// 4-edge prefetch streams, in-loop masks (R12's remainder-split cost VGPRs and
// occupancy — reverted). Zeroed gap records make unguarded prefetch safe.
// Max-free online softmax (logits bounded, glorot-scale inputs).
template <int H, int C, bool FUSE_HEADS>
__global__ __launch_bounds__(256)
void gat_kernel(const float* __restrict__ xl, const float* __restrict__ xr,
                const int* __restrict__ rs, const int* __restrict__ re,
                const int2* __restrict__ edges,
                const float* __restrict__ We, const float* __restrict__ att,
                const float* __restrict__ bias, float* __restrict__ hout,
                const float* __restrict__ wa, const float* __restrict__ ba,
                const float* __restrict__ wc, const float* __restrict__ bc,
                const float* __restrict__ ls, float* __restrict__ pout,
                int n) {
    constexpr int LPH = C / 4;
    if (FUSE_HEADS && blockIdx.x == 0 && threadIdx.x < 2)
        pout[(size_t)n * 2 + threadIdx.x] = expf(ls[threadIdx.x]);
    const int lane = threadIdx.x & 63;
    const int wid = (blockIdx.x * blockDim.x + threadIdx.x) >> 6;
    if (wid >= n) return;
    const int i = wid;
    const int g = lane >> 4;
    const int q = lane & 15;

    const float4* xl4 = (const float4*)xl;
    const float4 xri = ((const float4*)(xr + (size_t)i * 64))[q];
    const float4 we0 = ((const float4*)We)[q];
    const float4 we1 = ((const float4*)(We + 64))[q];
    float4 av = ((const float4*)att)[q];
    const float LOG2E = 1.4426950408889634f;
    av.x *= LOG2E; av.y *= LOG2E; av.z *= LOG2E; av.w *= LOG2E;

    float den = 0.f;
    float a0 = 0.f, a1 = 0.f, a2 = 0.f, a3 = 0.f;
    float s0 = 0.f, s1 = 0.f;

    const int e0 = rs[i], e1 = re[i];

    int2 rn0 = edges[e0 + g];
    int2 rn1 = edges[e0 + 4 + g];
    float4 xvn0 = xl4[(rn0.x << 4) + q];
    float4 xvn1 = xl4[(rn1.x << 4) + q];

    for (int eb = e0; eb < e1; eb += 8) {
        int2 r0 = rn0, r1 = rn1;
        float4 xv0 = xvn0, xv1 = xvn1;
        rn0 = edges[eb + 8 + g];
        rn1 = edges[eb + 12 + g];
        xvn0 = xl4[(rn0.x << 4) + q];
        xvn1 = xl4[(rn1.x << 4) + q];

        const bool v0 = (eb + g) < e1;
        const bool v1 = (eb + 4 + g) < e1;
        float ea00 = v0 ? __int_as_float(r0.y << 16) : 0.f;
        float ea01 = v0 ? __int_as_float(r0.y & 0xFFFF0000) : 0.f;
        float ea10 = v1 ? __int_as_float(r1.y << 16) : 0.f;
        float ea11 = v1 ? __int_as_float(r1.y & 0xFFFF0000) : 0.f;
        s0 += ea00 + ea10;
        s1 += ea01 + ea11;

        float y0 = xv0.x + fmaf(ea00, we0.x, fmaf(ea01, we1.x, xri.x));
        float y1 = xv0.y + fmaf(ea00, we0.y, fmaf(ea01, we1.y, xri.y));
        float y2 = xv0.z + fmaf(ea00, we0.z, fmaf(ea01, we1.z, xri.z));
        float y3 = xv0.w + fmaf(ea00, we0.w, fmaf(ea01, we1.w, xri.w));
        float u0 = xv1.x + fmaf(ea10, we0.x, fmaf(ea11, we1.x, xri.x));
        float u1 = xv1.y + fmaf(ea10, we0.y, fmaf(ea11, we1.y, xri.y));
        float u2 = xv1.z + fmaf(ea10, we0.z, fmaf(ea11, we1.z, xri.z));
        float u3 = xv1.w + fmaf(ea10, we0.w, fmaf(ea11, we1.w, xri.w));
        y0 = fmaxf(y0, 0.2f * y0); u0 = fmaxf(u0, 0.2f * u0);
        y1 = fmaxf(y1, 0.2f * y1); u1 = fmaxf(u1, 0.2f * u1);
        y2 = fmaxf(y2, 0.2f * y2); u2 = fmaxf(u2, 0.2f * u2);
        y3 = fmaxf(y3, 0.2f * y3); u3 = fmaxf(u3, 0.2f * u3);
        float l0 = fmaf(y0, av.x, fmaf(y1, av.y, fmaf(y2, av.z, y3 * av.w)));
        float l1 = fmaf(u0, av.x, fmaf(u1, av.y, fmaf(u2, av.z, u3 * av.w)));
#pragma unroll
        for (int m = 1; m < LPH; m <<= 1) {
            l0 += __shfl_xor(l0, m, 64);
            l1 += __shfl_xor(l1, m, 64);
        }
        float p0 = v0 ? exp2f(l0) : 0.f;
        float p1 = v1 ? exp2f(l1) : 0.f;
        den += p0 + p1;
        a0 = fmaf(p0, xv0.x, fmaf(p1, xv1.x, a0));
        a1 = fmaf(p0, xv0.y, fmaf(p1, xv1.y, a1));
        a2 = fmaf(p0, xv0.z, fmaf(p1, xv1.z, a2));
        a3 = fmaf(p0, xv0.w, fmaf(p1, xv1.w, a3));
    }

    // merge the 4 edge-slot groups — pure adds
#pragma unroll
    for (int m = 16; m < 64; m <<= 1) {
        den += __shfl_xor(den, m, 64);
        a0 += __shfl_xor(a0, m, 64);
        a1 += __shfl_xor(a1, m, 64);
        a2 += __shfl_xor(a2, m, 64);
        a3 += __shfl_xor(a3, m, 64);
        s0 += __shfl_xor(s0, m, 64);
        s1 += __shfl_xor(s1, m, 64);
    }

    // self-loop: attr = mean of incoming
    float degc = fmaxf((float)(e1 - e0), 1.0f);
    float la0 = s0 / degc, la1 = s1 / degc;
    const float4 xlv = xl4[(i << 4) + q];
    {
        float z0 = xlv.x + fmaf(la0, we0.x, fmaf(la1, we1.x, xri.x));
        float z1 = xlv.y + fmaf(la0, we0.y, fmaf(la1, we1.y, xri.y));
        float z2 = xlv.z + fmaf(la0, we0.z, fmaf(la1, we1.z, xri.z));
        float z3 = xlv.w + fmaf(la0, we0.w, fmaf(la1, we1.w, xri.w));
        z0 = fmaxf(z0, 0.2f * z0);
        z1 = fmaxf(z1, 0.2f * z1);
        z2 = fmaxf(z2, 0.2f * z2);
        z3 = fmaxf(z3, 0.2f * z3);
        float l = fmaf(z0, av.x, fmaf(z1, av.y, fmaf(z2, av.z, z3 * av.w)));
#pragma unroll
        for (int m = 1; m < LPH; m <<= 1) l += __shfl_xor(l, m, 64);
        float p = exp2f(l);
        den += p;
        a0 = fmaf(p, xlv.x, a0);
        a1 = fmaf(p, xlv.y, a1);
        a2 = fmaf(p, xlv.z, a2);
        a3 = fmaf(p, xlv.w, a3);
    }

    float rd = 1.0f / den;
    const float4 bv = ((const float4*)bias)[q];
    float4 o;
    o.x = fmaxf(fmaf(a0, rd, bv.x), 0.f);
    o.y = fmaxf(fmaf(a1, rd, bv.y), 0.f);
    o.z = fmaxf(fmaf(a2, rd, bv.z), 0.f);
    o.w = fmaxf(fmaf(a3, rd, bv.w), 0.f);

    if (!FUSE_HEADS) {
        if (g == 0) ((float4*)(hout + (size_t)i * 64))[q] = o;
    } else {
        float4 wa01 = ((const float4*)wa)[q * 2];
        float4 wa23 = ((const float4*)wa)[q * 2 + 1];
        float4 wcv  = ((const float4*)wc)[q];
        float d0 = o.x * wa01.x + o.y * wa01.z + o.z * wa23.x + o.w * wa23.z;
        float d1 = o.x * wa01.y + o.y * wa01.w + o.z * wa23.y + o.w * wa23.w;
        float d2 = o.x * wcv.x + o.y * wcv.y + o.z * wcv.z + o.w * wcv.w;
#pragma unroll
        for (int m = 1; m < 16; m <<= 1) {
            d0 += __shfl_xor(d0, m, 64);
            d1 += __shfl_xor(d1, m, 64);
            d2 += __shfl_xor(d2, m, 64);
        }
        if (lane == 0) {
            pout[(size_t)i * 2 + 0] = tanhf(d0 + ba[0]);
            pout[(size_t)i * 2 + 1] = tanhf(d1 + ba[1]);
            pout[(size_t)n * 2 + 2 + i] = d2 + bc[0];
        }
    }
}

// ---------------- launch ---------------------------------------------------

extern "C" void kernel_launch(void* const* d_in, const int* in_sizes, int n_in,
                              void* d_out, int out_size, void* d_ws, size_t ws_size,
                              hipStream_t stream) {
    const float* x    = (const float*)d_in[0];
    const int*   ei   = (const int*)  d_in[1];
    const float* ea   = (const float*)d_in[2];
    const float* w1l  = (const float*)d_in[3];
    const float* b1l  = (const float*)d_in[4];
    const float* w1r  = (const float*)d_in[5];
    const float* b1r  = (const float*)d_in[6];
    const float* w1e  = (const float*)d_in[7];
    const float* att1 = (const float*)d_in[8];
    const float* bias1= (const float*)d_in[9];
    const float* w2l  = (const float*)d_in[10];
    const float* b2l  = (const float*)d_in[11];
    const float* w2r  = (const float*)d_in[12];
    const float* b2r  = (const float*)d_in[13];
    const float* w2e  = (const float*)d_in[14];
    const float* att2 = (const float*)d_in[15];
    const float* bias2= (const float*)d_in[16];
    const float* wa   = (const float*)d_in[17];
    const float* ba   = (const float*)d_in[18];
    const float* wc   = (const float*)d_in[19];
    const float* bc   = (const float*)d_in[20];
    const float* ls   = (const float*)d_in[21];

    const int N = in_sizes[0] / DIN;
    const int E = in_sizes[2] / 2;
    const int* srcr = ei;
    const int* dstr = ei + E;

    const int NB = (N + 255) >> 8;           // node buckets (196)
    const int Ec = (E + 255) / 256;          // edges per chunk
    int cap = (E + NB - 1) / NB;             // bucket capacity, 1.25x mean
    cap = ((cap + cap / 4) + 63) & ~63;

    char* p = (char*)d_ws;
    auto alloc = [&](size_t bytes) -> void* {
        void* r = (void*)p;
        p += (bytes + 255) & ~(size_t)255;
        return r;
    };
    int*   cursor   = (int*)  alloc(256 * 4);
    int*   chunkoff = (int*)  alloc(256 * 256 * 4);
    int*   rank     = (int*)  alloc((size_t)E * 4);
    int*   rs       = (int*)  alloc((size_t)N * 4);
    int*   re       = (int*)  alloc((size_t)N * 4);
    int2*  edges    = (int2*) alloc(((size_t)NB * cap + 64) * 8);
    float* xl       = (float*)alloc((size_t)N * F1 * 4);
    float* xr       = (float*)alloc((size_t)N * F1 * 4);
    float* h1       = (float*)alloc((size_t)N * F1 * 4);
    float* h2       = (float*)alloc((size_t)N * F2 * 4);
    // inter (NB*cap*8 ~= 16.6 MB) aliases h1+h2 (25.6 MB); consumed by
    // bucket_csr before h1/h2 are written.
    int2* inter = (int2*)h1;
    (void)ws_size; (void)n_in; (void)out_size;

    hipMemsetAsync(cursor, 0, 256 * 4, stream);

    const int TB = 256;
    int gridGemm = (N + 31) / 32;
    int gridWave = (N + 3) / 4;

    fused_bcount_lin1<<<gridGemm + 256, TB, 0, stream>>>(
        dstr, cursor, chunkoff, rank, E, Ec, NB, gridGemm,
        x, w1l, b1l, w1r, b1r, xl, xr, N);
    scatter_buckets<<<256, 512, 0, stream>>>(srcr, dstr, ea, rank, chunkoff,
                                             inter, E, Ec, NB, cap);
    bucket_csr<<<NB, 512, 0, stream>>>(inter, cursor, rs, re, edges, NB, N, cap);

    gat_kernel<4, 16, false><<<gridWave, TB, 0, stream>>>(
        xl, xr, rs, re, edges, w1e, att1, bias1, h1,
        nullptr, nullptr, nullptr, nullptr, nullptr, nullptr, N);
    lin_lr_tiled64<<<gridGemm, TB, 0, stream>>>(h1, w2l, b2l, w2r, b2r, xl, xr, N);
    gat_kernel<2, 32, true><<<gridWave, TB, 0, stream>>>(
        xl, xr, rs, re, edges, w2e, att2, bias2, h2,
        wa, ba, wc, bc, ls, (float*)d_out, N);
}